// Round 7
// baseline (10496.227 us; speedup 1.0000x reference)
//
#include <hip/hip_runtime.h>
#include <hip/hip_bf16.h>
#include <math.h>

// Problem constants
#define N_TRAIN 4096
#define N_FEAT  64
#define NHID    256
#define ENC     256
#define GH      256
#define AH      64
#define NANTES  32768
#define TSTEPS  32

#define SSTR 528   // lstm setup LDS row stride (f32)
#define RSTR 68    // scores reduce LDS row stride (f32)

typedef __attribute__((ext_vector_type(8))) short bf16x8;
typedef __attribute__((ext_vector_type(4))) float f32x4;

__device__ __forceinline__ float sigmoidf_(float x) {
    return 1.0f / (1.0f + __expf(-x));
}
__device__ __forceinline__ float tanhf_(float x) {
    return 1.0f - 2.0f / (__expf(2.0f * x) + 1.0f);
}
__device__ __forceinline__ unsigned short f2bf_rne(float x) {
    unsigned int u = __float_as_uint(x);
    unsigned int r = u + 0x7FFFu + ((u >> 16) & 1u);
    return (unsigned short)(r >> 16);
}
__device__ __forceinline__ float bf2f(unsigned short b) {
    return __uint_as_float(((unsigned int)b) << 16);
}

// ---------------------------------------------------------------------------
// Kernel 0: zero the e-sum accumulator
// ---------------------------------------------------------------------------
__global__ void zero_kernel(float* __restrict__ esum) {
    int tid = blockIdx.x * blockDim.x + threadIdx.x;
    for (int i = tid; i < TSTEPS * GH; i += gridDim.x * blockDim.x)
        esum[i] = 0.0f;
}

// ---------------------------------------------------------------------------
// Kernel P: pack Whh (1024x256 f32) into MFMA-fragment-ordered bf16 (hi only).
// ---------------------------------------------------------------------------
__global__ void pack_whh(const float* __restrict__ Whh,
                         unsigned short* __restrict__ hi)
{
    int g = blockIdx.x * 256 + threadIdx.x;      // 0 .. 32767
    if (g >= 64 * 8 * 64) return;
    int lane  = g & 63;
    int ks    = (g >> 6) & 7;
    int ntile = g >> 9;
    int n  = ntile * 16 + (lane & 15);
    int k0 = ks * 32 + (lane >> 4) * 8;
    const float* src = Whh + n * 256 + k0;
    #pragma unroll
    for (int j = 0; j < 8; ++j)
        hi[g * 8 + j] = f2bf_rne(src[j]);
}

// ---------------------------------------------------------------------------
// Kernel A: fused encoder -> x_proj -> 32-step MFMA LSTM -> per-step h sums
// (unchanged from round 6)
// ---------------------------------------------------------------------------
__global__ __launch_bounds__(512, 4) void lstm_kernel(
    const float* __restrict__ ctx,
    const float* __restrict__ encW1, const float* __restrict__ encb1,
    const float* __restrict__ encW2, const float* __restrict__ encb2,
    const float* __restrict__ Wih,
    const float* __restrict__ bih,  const float* __restrict__ bhh,
    const unsigned short* __restrict__ Wph,
    float* __restrict__ esum)
{
    __shared__ float sbuf[16 * SSTR];      // 33792 B setup scratch
    __shared__ short hhi[2][16 * 256];     // 16 KB, XOR-swizzled cols
    __shared__ short hlo[2][16 * 256];     // 16 KB

    const int tid   = threadIdx.x;
    const int j     = tid & 255;
    const int rh    = tid >> 8;
    const int rbase = rh * 8;
    const int r0    = blockIdx.x * 16;

    // hid = relu(ctx @ encW1 + b1) -> sbuf cols [0,256)
    {
        float acc[8];
        float b = encb1[j];
        #pragma unroll
        for (int r = 0; r < 8; ++r) acc[r] = b;
        for (int k = 0; k < N_FEAT; ++k) {
            float w = encW1[k * NHID + j];
            #pragma unroll
            for (int r = 0; r < 8; ++r)
                acc[r] = fmaf(ctx[(r0 + rbase + r) * N_FEAT + k], w, acc[r]);
        }
        #pragma unroll
        for (int r = 0; r < 8; ++r)
            sbuf[(rbase + r) * SSTR + j] = fmaxf(acc[r], 0.0f);
    }
    __syncthreads();

    // phi = hid @ encW2 + b2 -> sbuf cols [264,520)
    {
        float p[8];
        float b = encb2[j];
        #pragma unroll
        for (int r = 0; r < 8; ++r) p[r] = b;
        for (int k = 0; k < NHID; ++k) {
            float w = encW2[k * ENC + j];
            #pragma unroll
            for (int r = 0; r < 8; ++r)
                p[r] = fmaf(sbuf[(rbase + r) * SSTR + k], w, p[r]);
        }
        __syncthreads();
        #pragma unroll
        for (int r = 0; r < 8; ++r)
            sbuf[(rbase + r) * SSTR + 264 + j] = p[r];
    }
    __syncthreads();

    // xp[g][r] in registers (reads phi)
    float xp[4][8];
    #pragma unroll
    for (int g = 0; g < 4; ++g) {
        int m = g * 256 + j;
        float b = bih[m] + bhh[m];
        #pragma unroll
        for (int r = 0; r < 8; ++r) xp[g][r] = b;
        const float4* wrow = (const float4*)(Wih + m * ENC);
        for (int k4 = 0; k4 < ENC / 4; ++k4) {
            float4 wv = wrow[k4];
            #pragma unroll
            for (int r = 0; r < 8; ++r) {
                const float* ph = &sbuf[(rbase + r) * SSTR + 264 + k4 * 4];
                float v = xp[g][r];
                v = fmaf(ph[0], wv.x, v);
                v = fmaf(ph[1], wv.y, v);
                v = fmaf(ph[2], wv.z, v);
                v = fmaf(ph[3], wv.w, v);
                xp[g][r] = v;
            }
        }
    }
    __syncthreads();   // phi consumed

    const int w    = tid >> 6;        // wave 0..7
    const int l    = tid & 63;
    const int col  = l & 15;          // C col / A row
    const int kp   = l >> 4;          // 0..3
    const int arow = col;
    const int asw  = (arow & 7) << 3; // short-unit XOR swizzle

    // transfer xp -> C-fragment layout via sbuf cols [0,256), one gate at a time
    f32x4 xpf[4][2];
    #pragma unroll 1
    for (int g = 0; g < 4; ++g) {
        #pragma unroll
        for (int r = 0; r < 8; ++r)
            sbuf[(rbase + r) * SSTR + j] = xp[g][r];
        __syncthreads();
        #pragma unroll
        for (int u = 0; u < 2; ++u)
            #pragma unroll
            for (int q = 0; q < 4; ++q)
                xpf[g][u][q] = sbuf[(kp * 4 + q) * SSTR + w * 32 + u * 16 + col];
        __syncthreads();
    }

    for (int i = tid; i < 16 * 256; i += 512) { hhi[0][i] = 0; hlo[0][i] = 0; }
    __syncthreads();

    const unsigned short* Bh = Wph + (size_t)l * 8;

    float c[2][4];
    #pragma unroll
    for (int u = 0; u < 2; ++u)
        #pragma unroll
        for (int q = 0; q < 4; ++q) c[u][q] = 0.0f;

    for (int t = 0; t < TSTEPS; ++t) {
        const short* Ahi = hhi[t & 1];
        const short* Alo = hlo[t & 1];
        short* Nhi = hhi[(t + 1) & 1];
        short* Nlo = hlo[(t + 1) & 1];

        float su[2];
        #pragma unroll 1
        for (int u = 0; u < 2; ++u) {
            f32x4 acc[4];
            #pragma unroll
            for (int g = 0; g < 4; ++g) acc[g] = xpf[g][u];

            #pragma unroll 2
            for (int ks = 0; ks < 8; ++ks) {
                bf16x8 bh[4];
                #pragma unroll
                for (int g = 0; g < 4; ++g)
                    bh[g] = *(const bf16x8*)(Bh +
                        (size_t)(((16 * g + 2 * w + u) * 8 + ks) * 64) * 8);
                bf16x8 ah = *(const bf16x8*)&Ahi[arow * 256 +
                                ((ks * 32 + kp * 8) ^ asw)];
                bf16x8 al = *(const bf16x8*)&Alo[arow * 256 +
                                ((ks * 32 + kp * 8) ^ asw)];
                #pragma unroll
                for (int g = 0; g < 4; ++g) {
                    acc[g] = __builtin_amdgcn_mfma_f32_16x16x32_bf16(al, bh[g], acc[g], 0, 0, 0);
                    acc[g] = __builtin_amdgcn_mfma_f32_16x16x32_bf16(ah, bh[g], acc[g], 0, 0, 0);
                }
            }

            float s = 0.0f;
            #pragma unroll
            for (int q = 0; q < 4; ++q) {
                float iv = sigmoidf_(acc[0][q]);
                float fv = sigmoidf_(acc[1][q]);
                float gv = tanhf_   (acc[2][q]);
                float ov = sigmoidf_(acc[3][q]);
                c[u][q] = fv * c[u][q] + iv * gv;
                float hv = ov * tanhf_(c[u][q]);
                s += hv;
                unsigned short h16 = f2bf_rne(hv);
                float lof = hv - bf2f(h16);
                int row  = kp * 4 + q;
                int hcol = w * 32 + u * 16 + col;
                int sidx = row * 256 + (hcol ^ ((row & 7) << 3));
                Nhi[sidx] = (short)h16;
                Nlo[sidx] = (short)f2bf_rne(lof);
            }
            su[u] = s;
        }

        #pragma unroll
        for (int u = 0; u < 2; ++u) {
            float v = su[u];
            v += __shfl_xor(v, 16);
            v += __shfl_xor(v, 32);
            if (l < 16)
                atomicAdd(&esum[t * GH + w * 32 + u * 16 + l], v);
        }
        __syncthreads();
    }
}

// ---------------------------------------------------------------------------
// Kernel C: proj[t][c] = (esum[t]/4096) @ W1_h + att_b1[c]
// ---------------------------------------------------------------------------
__global__ void proj_kernel(const float* __restrict__ esum,
                            const float* __restrict__ attW1,
                            const float* __restrict__ attb1,
                            float* __restrict__ proj)
{
    __shared__ float part[4][AH];
    const int t   = blockIdx.x;
    const int cix = threadIdx.x & 63;
    const int g   = threadIdx.x >> 6;
    float a = 0.0f;
    #pragma unroll 4
    for (int k = g * 64; k < g * 64 + 64; ++k) {
        float e = esum[t * GH + k] * (1.0f / (float)N_TRAIN);
        a = fmaf(e, attW1[(size_t)(N_TRAIN + k) * AH + cix], a);
    }
    part[g][cix] = a;
    __syncthreads();
    if (threadIdx.x < AH)
        proj[t * AH + cix] = part[0][cix] + part[1][cix] + part[2][cix] +
                             part[3][cix] + attb1[cix];
}

// ---------------------------------------------------------------------------
// Kernel D: S_proj fused with per-step scores — barrier-free K loop.
// Grid: 512 blocks x 256 threads. Thread = (ai = tid&63 -> ante a0+ai,
// kq = tid>>6 = wave index -> K rows [kq*1024, kq*1024+1024)).
// Each thread: 64 f32 accumulators; w read via wave-uniform scalar loads
// (s_load -> SGPR, no LDS staging, no barriers); S prefetched 16-deep.
// End: LDS reduce over 4 k-quarters, then 32-step epilogue.
// ---------------------------------------------------------------------------
__global__ __launch_bounds__(256, 2) void scores_kernel(
    const float* __restrict__ S,
    const float* __restrict__ attW1,
    const float* __restrict__ proj,
    const float* __restrict__ attw2,
    const float* __restrict__ attb2,
    float* __restrict__ out)
{
    __shared__ float red[64 * RSTR];     // 17408 B reduce / sp buffer
    __shared__ float projl[TSTEPS * AH]; // 8 KB
    __shared__ float w2l[AH];
    __shared__ float part[256];

    const int tid = threadIdx.x;
    const int ai  = tid & 63;
    const int kq  = tid >> 6;            // wave index = K quarter
    const int a0  = blockIdx.x * 64;
    const int a   = a0 + ai;
    const int rowbase = kq * 1024;

    float acc[64];
    #pragma unroll
    for (int c = 0; c < 64; ++c) acc[c] = 0.0f;

    const float* Scol = S + (size_t)rowbase * NANTES + a;

#define LOADS(dst, base_row) do {                                            \
        _Pragma("unroll") for (int i = 0; i < 16; ++i)                       \
            dst[i] = Scol[(size_t)((base_row) + i) * NANTES];                \
    } while (0)

// w rows are wave-uniform -> scalar loads; FMA takes SGPR operand directly.
#define COMPS(src, base_row) do {                                            \
        _Pragma("unroll") for (int i = 0; i < 16; ++i) {                     \
            float s = src[i];                                                \
            const float4* wrow = (const float4*)(attW1 +                     \
                (size_t)(rowbase + (base_row) + i) * AH);                    \
            _Pragma("unroll") for (int c4 = 0; c4 < 16; ++c4) {              \
                float4 wv = wrow[c4];                                        \
                acc[c4 * 4 + 0] = fmaf(s, wv.x, acc[c4 * 4 + 0]);            \
                acc[c4 * 4 + 1] = fmaf(s, wv.y, acc[c4 * 4 + 1]);            \
                acc[c4 * 4 + 2] = fmaf(s, wv.z, acc[c4 * 4 + 2]);            \
                acc[c4 * 4 + 3] = fmaf(s, wv.w, acc[c4 * 4 + 3]);            \
            }                                                                \
        }                                                                    \
    } while (0)

    {
        float sA[16], sB[16];
        LOADS(sA, 0);
        #pragma unroll 1
        for (int c2 = 0; c2 < 32; ++c2) {
            const int ch = 2 * c2;
            LOADS(sB, (ch + 1) * 16);
            COMPS(sA, ch * 16);
            if (c2 < 31) LOADS(sA, (ch + 2) * 16);
            COMPS(sB, (ch + 1) * 16);
        }
    }
#undef LOADS
#undef COMPS

    // ---- reduce the 4 k-quarters (3 sequential phases into kq==0) ----
    __syncthreads();
    #pragma unroll 1
    for (int p = 1; p < 4; ++p) {
        if (kq == p)
            #pragma unroll
            for (int c = 0; c < 64; ++c) red[ai * RSTR + c] = acc[c];
        __syncthreads();
        if (kq == 0)
            #pragma unroll
            for (int c = 0; c < 64; ++c) acc[c] += red[ai * RSTR + c];
        __syncthreads();
    }
    if (kq == 0)
        #pragma unroll
        for (int c = 0; c < 64; ++c) red[ai * RSTR + c] = acc[c];

    for (int t = tid; t < TSTEPS * AH; t += 256) projl[t] = proj[t];
    if (tid < AH) w2l[tid] = attw2[tid];
    __syncthreads();

    // each thread finalizes cols [kq*16, kq*16+16) of its ante
    float sp[16];
    #pragma unroll
    for (int q = 0; q < 16; ++q) sp[q] = red[ai * RSTR + kq * 16 + q];

    const float b2v = attb2[0];
    for (int t = 0; t < TSTEPS; ++t) {
        float s = 0.0f;
        const float* pr  = &projl[t * AH + kq * 16];
        const float* w2p = &w2l[kq * 16];
        #pragma unroll
        for (int q = 0; q < 16; ++q)
            s += fmaxf(sp[q] + pr[q], 0.0f) * w2p[q];
        part[tid] = s;
        __syncthreads();
        if (tid < 64)
            out[(size_t)t * NANTES + a0 + tid] =
                part[tid] + part[tid + 64] + part[tid + 128] + part[tid + 192] + b2v;
        __syncthreads();
    }
}

// ---------------------------------------------------------------------------
// Kernel E: per-step argmax (first-max semantics).
// ---------------------------------------------------------------------------
__global__ void argmax_kernel(const float* __restrict__ scores,
                              float* __restrict__ out)
{
    __shared__ float bv[256];
    __shared__ int   bidx[256];
    const int t = blockIdx.x, tid = threadIdx.x;
    float best = -INFINITY;
    int   bi   = 0x7fffffff;
    for (int a = tid; a < NANTES; a += 256) {
        float v = scores[(size_t)t * NANTES + a];
        if (v > best) { best = v; bi = a; }
    }
    bv[tid] = best; bidx[tid] = bi;
    __syncthreads();
    for (int s = 128; s > 0; s >>= 1) {
        if (tid < s) {
            if (bv[tid + s] > bv[tid] ||
                (bv[tid + s] == bv[tid] && bidx[tid + s] < bidx[tid])) {
                bv[tid] = bv[tid + s];
                bidx[tid] = bidx[tid + s];
            }
        }
        __syncthreads();
    }
    if (tid == 0)
        out[(size_t)TSTEPS * NANTES + t] = (float)bidx[0];
}

// ---------------------------------------------------------------------------
extern "C" void kernel_launch(void* const* d_in, const int* in_sizes, int n_in,
                              void* d_out, int out_size, void* d_ws, size_t ws_size,
                              hipStream_t stream)
{
    const float* ctx   = (const float*)d_in[0];
    const float* S     = (const float*)d_in[1];
    const float* encW1 = (const float*)d_in[2];
    const float* encb1 = (const float*)d_in[3];
    const float* encW2 = (const float*)d_in[4];
    const float* encb2 = (const float*)d_in[5];
    const float* Wih   = (const float*)d_in[6];
    const float* Whh   = (const float*)d_in[7];
    const float* bih   = (const float*)d_in[8];
    const float* bhh   = (const float*)d_in[9];
    const float* attW1 = (const float*)d_in[10];
    const float* attb1 = (const float*)d_in[11];
    const float* attw2 = (const float*)d_in[12];
    const float* attb2 = (const float*)d_in[13];

    char* ws = (char*)d_ws;
    float* esum = (float*)ws;                                // 32 KB
    float* proj = (float*)(ws + 32768);                      // 8 KB
    unsigned short* Wph = (unsigned short*)(ws + 40960);     // 512 KB
    float* out  = (float*)d_out;

    zero_kernel<<<dim3(8), dim3(256), 0, stream>>>(esum);
    pack_whh<<<dim3(128), dim3(256), 0, stream>>>(Whh, Wph);
    lstm_kernel<<<dim3(N_TRAIN / 16), dim3(512), 0, stream>>>(
        ctx, encW1, encb1, encW2, encb2, Wih, bih, bhh, Wph, esum);
    proj_kernel<<<dim3(TSTEPS), dim3(256), 0, stream>>>(esum, attW1, attb1, proj);
    scores_kernel<<<dim3(NANTES / 64), dim3(256), 0, stream>>>(
        S, attW1, proj, attw2, attb2, out);
    argmax_kernel<<<dim3(TSTEPS), dim3(256), 0, stream>>>(out, out);
}

// Round 8
// 822.045 us; speedup vs baseline: 12.7684x; 12.7684x over previous
//
#include <hip/hip_runtime.h>
#include <hip/hip_bf16.h>
#include <math.h>

// Problem constants
#define N_TRAIN 4096
#define N_FEAT  64
#define NHID    256
#define ENC     256
#define GH      256
#define AH      64
#define NANTES  32768
#define TSTEPS  32

#define SSTR 528   // lstm setup LDS row stride (f32)
#define CHUNK 128  // scores K-chunk rows

typedef __attribute__((ext_vector_type(8))) short bf16x8;
typedef __attribute__((ext_vector_type(4))) float f32x4;

__device__ __forceinline__ float sigmoidf_(float x) {
    return 1.0f / (1.0f + __expf(-x));
}
__device__ __forceinline__ float tanhf_(float x) {
    return 1.0f - 2.0f / (__expf(2.0f * x) + 1.0f);
}
__device__ __forceinline__ unsigned short f2bf_rne(float x) {
    unsigned int u = __float_as_uint(x);
    unsigned int r = u + 0x7FFFu + ((u >> 16) & 1u);
    return (unsigned short)(r >> 16);
}
__device__ __forceinline__ float bf2f(unsigned short b) {
    return __uint_as_float(((unsigned int)b) << 16);
}

// ---------------------------------------------------------------------------
// Kernel 0: zero the e-sum accumulator
// ---------------------------------------------------------------------------
__global__ void zero_kernel(float* __restrict__ esum) {
    int tid = blockIdx.x * blockDim.x + threadIdx.x;
    for (int i = tid; i < TSTEPS * GH; i += gridDim.x * blockDim.x)
        esum[i] = 0.0f;
}

// ---------------------------------------------------------------------------
// Kernel P: pack Whh (1024x256 f32) into MFMA-fragment-ordered bf16 (hi only).
// ---------------------------------------------------------------------------
__global__ void pack_whh(const float* __restrict__ Whh,
                         unsigned short* __restrict__ hi)
{
    int g = blockIdx.x * 256 + threadIdx.x;      // 0 .. 32767
    if (g >= 64 * 8 * 64) return;
    int lane  = g & 63;
    int ks    = (g >> 6) & 7;
    int ntile = g >> 9;
    int n  = ntile * 16 + (lane & 15);
    int k0 = ks * 32 + (lane >> 4) * 8;
    const float* src = Whh + n * 256 + k0;
    #pragma unroll
    for (int j = 0; j < 8; ++j)
        hi[g * 8 + j] = f2bf_rne(src[j]);
}

// ---------------------------------------------------------------------------
// Kernel A: fused encoder -> x_proj -> 32-step MFMA LSTM -> per-step h sums
// (unchanged from round 6 — benched without scratch traffic)
// ---------------------------------------------------------------------------
__global__ __launch_bounds__(512, 4) void lstm_kernel(
    const float* __restrict__ ctx,
    const float* __restrict__ encW1, const float* __restrict__ encb1,
    const float* __restrict__ encW2, const float* __restrict__ encb2,
    const float* __restrict__ Wih,
    const float* __restrict__ bih,  const float* __restrict__ bhh,
    const unsigned short* __restrict__ Wph,
    float* __restrict__ esum)
{
    __shared__ float sbuf[16 * SSTR];      // 33792 B setup scratch
    __shared__ short hhi[2][16 * 256];     // 16 KB, XOR-swizzled cols
    __shared__ short hlo[2][16 * 256];     // 16 KB

    const int tid   = threadIdx.x;
    const int j     = tid & 255;
    const int rh    = tid >> 8;
    const int rbase = rh * 8;
    const int r0    = blockIdx.x * 16;

    // hid = relu(ctx @ encW1 + b1) -> sbuf cols [0,256)
    {
        float acc[8];
        float b = encb1[j];
        #pragma unroll
        for (int r = 0; r < 8; ++r) acc[r] = b;
        for (int k = 0; k < N_FEAT; ++k) {
            float w = encW1[k * NHID + j];
            #pragma unroll
            for (int r = 0; r < 8; ++r)
                acc[r] = fmaf(ctx[(r0 + rbase + r) * N_FEAT + k], w, acc[r]);
        }
        #pragma unroll
        for (int r = 0; r < 8; ++r)
            sbuf[(rbase + r) * SSTR + j] = fmaxf(acc[r], 0.0f);
    }
    __syncthreads();

    // phi = hid @ encW2 + b2 -> sbuf cols [264,520)
    {
        float p[8];
        float b = encb2[j];
        #pragma unroll
        for (int r = 0; r < 8; ++r) p[r] = b;
        for (int k = 0; k < NHID; ++k) {
            float w = encW2[k * ENC + j];
            #pragma unroll
            for (int r = 0; r < 8; ++r)
                p[r] = fmaf(sbuf[(rbase + r) * SSTR + k], w, p[r]);
        }
        __syncthreads();
        #pragma unroll
        for (int r = 0; r < 8; ++r)
            sbuf[(rbase + r) * SSTR + 264 + j] = p[r];
    }
    __syncthreads();

    // xp[g][r] in registers (reads phi)
    float xp[4][8];
    #pragma unroll
    for (int g = 0; g < 4; ++g) {
        int m = g * 256 + j;
        float b = bih[m] + bhh[m];
        #pragma unroll
        for (int r = 0; r < 8; ++r) xp[g][r] = b;
        const float4* wrow = (const float4*)(Wih + m * ENC);
        for (int k4 = 0; k4 < ENC / 4; ++k4) {
            float4 wv = wrow[k4];
            #pragma unroll
            for (int r = 0; r < 8; ++r) {
                const float* ph = &sbuf[(rbase + r) * SSTR + 264 + k4 * 4];
                float v = xp[g][r];
                v = fmaf(ph[0], wv.x, v);
                v = fmaf(ph[1], wv.y, v);
                v = fmaf(ph[2], wv.z, v);
                v = fmaf(ph[3], wv.w, v);
                xp[g][r] = v;
            }
        }
    }
    __syncthreads();   // phi consumed

    const int w    = tid >> 6;        // wave 0..7
    const int l    = tid & 63;
    const int col  = l & 15;          // C col / A row
    const int kp   = l >> 4;          // 0..3
    const int arow = col;
    const int asw  = (arow & 7) << 3; // short-unit XOR swizzle

    // transfer xp -> C-fragment layout via sbuf cols [0,256), one gate at a time
    f32x4 xpf[4][2];
    #pragma unroll 1
    for (int g = 0; g < 4; ++g) {
        #pragma unroll
        for (int r = 0; r < 8; ++r)
            sbuf[(rbase + r) * SSTR + j] = xp[g][r];
        __syncthreads();
        #pragma unroll
        for (int u = 0; u < 2; ++u)
            #pragma unroll
            for (int q = 0; q < 4; ++q)
                xpf[g][u][q] = sbuf[(kp * 4 + q) * SSTR + w * 32 + u * 16 + col];
        __syncthreads();
    }

    for (int i = tid; i < 16 * 256; i += 512) { hhi[0][i] = 0; hlo[0][i] = 0; }
    __syncthreads();

    const unsigned short* Bh = Wph + (size_t)l * 8;

    float c[2][4];
    #pragma unroll
    for (int u = 0; u < 2; ++u)
        #pragma unroll
        for (int q = 0; q < 4; ++q) c[u][q] = 0.0f;

    for (int t = 0; t < TSTEPS; ++t) {
        const short* Ahi = hhi[t & 1];
        const short* Alo = hlo[t & 1];
        short* Nhi = hhi[(t + 1) & 1];
        short* Nlo = hlo[(t + 1) & 1];

        float su[2];
        #pragma unroll 1
        for (int u = 0; u < 2; ++u) {
            f32x4 acc[4];
            #pragma unroll
            for (int g = 0; g < 4; ++g) acc[g] = xpf[g][u];

            #pragma unroll 2
            for (int ks = 0; ks < 8; ++ks) {
                bf16x8 bh[4];
                #pragma unroll
                for (int g = 0; g < 4; ++g)
                    bh[g] = *(const bf16x8*)(Bh +
                        (size_t)(((16 * g + 2 * w + u) * 8 + ks) * 64) * 8);
                bf16x8 ah = *(const bf16x8*)&Ahi[arow * 256 +
                                ((ks * 32 + kp * 8) ^ asw)];
                bf16x8 al = *(const bf16x8*)&Alo[arow * 256 +
                                ((ks * 32 + kp * 8) ^ asw)];
                #pragma unroll
                for (int g = 0; g < 4; ++g) {
                    acc[g] = __builtin_amdgcn_mfma_f32_16x16x32_bf16(al, bh[g], acc[g], 0, 0, 0);
                    acc[g] = __builtin_amdgcn_mfma_f32_16x16x32_bf16(ah, bh[g], acc[g], 0, 0, 0);
                }
            }

            float s = 0.0f;
            #pragma unroll
            for (int q = 0; q < 4; ++q) {
                float iv = sigmoidf_(acc[0][q]);
                float fv = sigmoidf_(acc[1][q]);
                float gv = tanhf_   (acc[2][q]);
                float ov = sigmoidf_(acc[3][q]);
                c[u][q] = fv * c[u][q] + iv * gv;
                float hv = ov * tanhf_(c[u][q]);
                s += hv;
                unsigned short h16 = f2bf_rne(hv);
                float lof = hv - bf2f(h16);
                int row  = kp * 4 + q;
                int hcol = w * 32 + u * 16 + col;
                int sidx = row * 256 + (hcol ^ ((row & 7) << 3));
                Nhi[sidx] = (short)h16;
                Nlo[sidx] = (short)f2bf_rne(lof);
            }
            su[u] = s;
        }

        #pragma unroll
        for (int u = 0; u < 2; ++u) {
            float v = su[u];
            v += __shfl_xor(v, 16);
            v += __shfl_xor(v, 32);
            if (l < 16)
                atomicAdd(&esum[t * GH + w * 32 + u * 16 + l], v);
        }
        __syncthreads();
    }
}

// ---------------------------------------------------------------------------
// Kernel C: proj[t][c] = (esum[t]/4096) @ W1_h + att_b1[c]
// ---------------------------------------------------------------------------
__global__ void proj_kernel(const float* __restrict__ esum,
                            const float* __restrict__ attW1,
                            const float* __restrict__ attb1,
                            float* __restrict__ proj)
{
    __shared__ float part[4][AH];
    const int t   = blockIdx.x;
    const int cix = threadIdx.x & 63;
    const int g   = threadIdx.x >> 6;
    float a = 0.0f;
    #pragma unroll 4
    for (int k = g * 64; k < g * 64 + 64; ++k) {
        float e = esum[t * GH + k] * (1.0f / (float)N_TRAIN);
        a = fmaf(e, attW1[(size_t)(N_TRAIN + k) * AH + cix], a);
    }
    part[g][cix] = a;
    __syncthreads();
    if (threadIdx.x < AH)
        proj[t * AH + cix] = part[0][cix] + part[1][cix] + part[2][cix] +
                             part[3][cix] + attb1[cix];
}

// ---------------------------------------------------------------------------
// Kernel D: S_proj fused with per-step scores.
// Grid: 256 blocks x 512 threads. Block owns 128 antes.
// Thread: ai = tid&31 -> antes a0+ai*4 (float4 S loads), cg = tid>>5 ->
// cols [cg*4, cg*4+4). acc = 4 antes x 4 cols = 16 regs.
// Per K row: one float4 S load + one ds_read_b128 of w (broadcast) + 16 FMA.
// attW1 staged in 128-row LDS chunks; 8-row ping-pong S prefetch inside.
// Epilogue: per-t partial dot, LDS reduce over 16 col-groups.
// ---------------------------------------------------------------------------
__global__ __launch_bounds__(512, 2) void scores_kernel(
    const float* __restrict__ S,
    const float* __restrict__ attW1,
    const float* __restrict__ proj,
    const float* __restrict__ attw2,
    const float* __restrict__ attb2,
    float* __restrict__ out)
{
    __shared__ float wl[CHUNK * AH];     // 32 KB: 128-row chunk of att_W1
    __shared__ float projl[TSTEPS * AH]; // 8 KB
    __shared__ float w2l[AH];
    __shared__ float part[16][132];      // 8.25 KB reduce buffer

    const int tid = threadIdx.x;
    const int ai  = tid & 31;            // ante quad
    const int cg  = tid >> 5;            // 0..15, cols cg*4..+4
    const int a0  = blockIdx.x * 128;
    const int a   = a0 + ai * 4;

    float acc[4][4];
    #pragma unroll
    for (int x = 0; x < 4; ++x)
        #pragma unroll
        for (int q = 0; q < 4; ++q) acc[x][q] = 0.0f;

    const float* Sp = S + a;

#define LS(dst, base_) do {                                                  \
        _Pragma("unroll") for (int i = 0; i < 4; ++i)                        \
            dst[i] = *(const float4*)(Sp + (size_t)((base_) + i) * NANTES);  \
    } while (0)

#define CS(src, base_) do {                                                  \
        _Pragma("unroll") for (int i = 0; i < 4; ++i) {                      \
            float4 wv = *(const float4*)&wl[((base_) + i) * AH + cg * 4];    \
            float4 s4 = src[i];                                              \
            acc[0][0] = fmaf(s4.x, wv.x, acc[0][0]);                         \
            acc[0][1] = fmaf(s4.x, wv.y, acc[0][1]);                         \
            acc[0][2] = fmaf(s4.x, wv.z, acc[0][2]);                         \
            acc[0][3] = fmaf(s4.x, wv.w, acc[0][3]);                         \
            acc[1][0] = fmaf(s4.y, wv.x, acc[1][0]);                         \
            acc[1][1] = fmaf(s4.y, wv.y, acc[1][1]);                         \
            acc[1][2] = fmaf(s4.y, wv.z, acc[1][2]);                         \
            acc[1][3] = fmaf(s4.y, wv.w, acc[1][3]);                         \
            acc[2][0] = fmaf(s4.z, wv.x, acc[2][0]);                         \
            acc[2][1] = fmaf(s4.z, wv.y, acc[2][1]);                         \
            acc[2][2] = fmaf(s4.z, wv.z, acc[2][2]);                         \
            acc[2][3] = fmaf(s4.z, wv.w, acc[2][3]);                         \
            acc[3][0] = fmaf(s4.w, wv.x, acc[3][0]);                         \
            acc[3][1] = fmaf(s4.w, wv.y, acc[3][1]);                         \
            acc[3][2] = fmaf(s4.w, wv.z, acc[3][2]);                         \
            acc[3][3] = fmaf(s4.w, wv.w, acc[3][3]);                         \
        }                                                                    \
    } while (0)

    #pragma unroll 1
    for (int c = 0; c < N_TRAIN / CHUNK; ++c) {
        __syncthreads();   // previous chunk fully consumed
        {   // stage 128x64 f32 chunk of att_W1 (32 KB, contiguous)
            const float4* src = (const float4*)(attW1 + (size_t)c * CHUNK * AH);
            float4* dstv = (float4*)wl;
            #pragma unroll
            for (int i = 0; i < 4; ++i)
                dstv[tid + i * 512] = src[tid + i * 512];
        }
        __syncthreads();

        const int rb = c * CHUNK;   // global row base (for S only)
        float4 sA[4], sB[4];
        LS(sA, rb + 0);
        #pragma unroll 1
        for (int g = 0; g < CHUNK / 8; ++g) {
            LS(sB, rb + g * 8 + 4);
            CS(sA, g * 8);
            if (g < CHUNK / 8 - 1) LS(sA, rb + g * 8 + 8);
            CS(sB, g * 8 + 4);
        }
    }
#undef LS
#undef CS

    __syncthreads();
    for (int t = tid; t < TSTEPS * AH; t += 512) projl[t] = proj[t];
    if (tid < AH) w2l[tid] = attw2[tid];
    __syncthreads();

    const float b2v = attb2[0];
    #pragma unroll 1
    for (int t = 0; t < TSTEPS; ++t) {
        const float* pr  = &projl[t * AH + cg * 4];
        const float* w2p = &w2l[cg * 4];
        #pragma unroll
        for (int x = 0; x < 4; ++x) {
            float s = 0.0f;
            #pragma unroll
            for (int q = 0; q < 4; ++q)
                s += fmaxf(acc[x][q] + pr[q], 0.0f) * w2p[q];
            part[cg][ai * 4 + x] = s;
        }
        __syncthreads();
        if (tid < 128) {
            float v = b2v;
            #pragma unroll
            for (int g = 0; g < 16; ++g) v += part[g][tid];
            out[(size_t)t * NANTES + a0 + tid] = v;
        }
        __syncthreads();
    }
}

// ---------------------------------------------------------------------------
// Kernel E: per-step argmax (first-max semantics).
// ---------------------------------------------------------------------------
__global__ void argmax_kernel(const float* __restrict__ scores,
                              float* __restrict__ out)
{
    __shared__ float bv[256];
    __shared__ int   bidx[256];
    const int t = blockIdx.x, tid = threadIdx.x;
    float best = -INFINITY;
    int   bi   = 0x7fffffff;
    for (int a = tid; a < NANTES; a += 256) {
        float v = scores[(size_t)t * NANTES + a];
        if (v > best) { best = v; bi = a; }
    }
    bv[tid] = best; bidx[tid] = bi;
    __syncthreads();
    for (int s = 128; s > 0; s >>= 1) {
        if (tid < s) {
            if (bv[tid + s] > bv[tid] ||
                (bv[tid + s] == bv[tid] && bidx[tid + s] < bidx[tid])) {
                bv[tid] = bv[tid + s];
                bidx[tid] = bidx[tid + s];
            }
        }
        __syncthreads();
    }
    if (tid == 0)
        out[(size_t)TSTEPS * NANTES + t] = (float)bidx[0];
}

// ---------------------------------------------------------------------------
extern "C" void kernel_launch(void* const* d_in, const int* in_sizes, int n_in,
                              void* d_out, int out_size, void* d_ws, size_t ws_size,
                              hipStream_t stream)
{
    const float* ctx   = (const float*)d_in[0];
    const float* S     = (const float*)d_in[1];
    const float* encW1 = (const float*)d_in[2];
    const float* encb1 = (const float*)d_in[3];
    const float* encW2 = (const float*)d_in[4];
    const float* encb2 = (const float*)d_in[5];
    const float* Wih   = (const float*)d_in[6];
    const float* Whh   = (const float*)d_in[7];
    const float* bih   = (const float*)d_in[8];
    const float* bhh   = (const float*)d_in[9];
    const float* attW1 = (const float*)d_in[10];
    const float* attb1 = (const float*)d_in[11];
    const float* attw2 = (const float*)d_in[12];
    const float* attb2 = (const float*)d_in[13];

    char* ws = (char*)d_ws;
    float* esum = (float*)ws;                                // 32 KB
    float* proj = (float*)(ws + 32768);                      // 8 KB
    unsigned short* Wph = (unsigned short*)(ws + 40960);     // 512 KB
    float* out  = (float*)d_out;

    zero_kernel<<<dim3(8), dim3(256), 0, stream>>>(esum);
    pack_whh<<<dim3(128), dim3(256), 0, stream>>>(Whh, Wph);
    lstm_kernel<<<dim3(N_TRAIN / 16), dim3(512), 0, stream>>>(
        ctx, encW1, encb1, encW2, encb2, Wih, bih, bhh, Wph, esum);
    proj_kernel<<<dim3(TSTEPS), dim3(256), 0, stream>>>(esum, attW1, attb1, proj);
    scores_kernel<<<dim3(NANTES / 128), dim3(512), 0, stream>>>(
        S, attW1, proj, attw2, attb2, out);
    argmax_kernel<<<dim3(TSTEPS), dim3(256), 0, stream>>>(out, out);
}